// Round 2
// baseline (621.825 us; speedup 1.0000x reference)
//
#include <hip/hip_runtime.h>
#include <cstddef>

#define IN_F 256
#define OUT_F 128
#define SCAN_CHUNK 1024

// ---------------- GEMM: support = X @ W  (fp32, vector FMA) ----------------
// BM=32 rows, BN=128 cols (=OUT_F), BK=64. 256 threads; each thread 4x4 outputs.
__global__ __launch_bounds__(256) void gemm_kernel(const float* __restrict__ X,
                                                   const float* __restrict__ W,
                                                   float* __restrict__ S,
                                                   int nrows) {
    __shared__ float Xs[64][36];   // [k][row], +4 pad: conflict-free b128 reads
    __shared__ float Ws[64][128];  // [k][col]
    const int t = threadIdx.x;
    const int bm = blockIdx.x * 32;
    const int c4 = (t & 31) * 4;
    const int r4 = (t >> 5) * 4;
    float acc[4][4] = {{0.f, 0.f, 0.f, 0.f}};

    for (int kt = 0; kt < IN_F; kt += 64) {
        // stage X tile (transposed into LDS: Xs[k][r])
#pragma unroll
        for (int l = 0; l < 2; ++l) {
            const int r = t & 31;
            const int km = (t >> 5) + l * 8;  // float4 index along k: 0..15
            int rr = bm + r; if (rr >= nrows) rr = nrows - 1;
            const float4 v = *reinterpret_cast<const float4*>(
                &X[(size_t)rr * IN_F + kt + km * 4]);
            Xs[km * 4 + 0][r] = v.x;
            Xs[km * 4 + 1][r] = v.y;
            Xs[km * 4 + 2][r] = v.z;
            Xs[km * 4 + 3][r] = v.w;
        }
        // stage W tile (row-major, linear float4 copy — coalesced, conflict-free)
#pragma unroll
        for (int l = 0; l < 8; ++l) {
            const int q = t + l * 256;
            const int k = q >> 5;
            const int c = (q & 31) * 4;
            *reinterpret_cast<float4*>(&Ws[k][c]) =
                *reinterpret_cast<const float4*>(&W[(size_t)(kt + k) * OUT_F + c]);
        }
        __syncthreads();
#pragma unroll 8
        for (int kk = 0; kk < 64; ++kk) {
            const float4 wv = *reinterpret_cast<const float4*>(&Ws[kk][c4]);
            const float4 xv = *reinterpret_cast<const float4*>(&Xs[kk][r4]);
            acc[0][0] += xv.x * wv.x; acc[0][1] += xv.x * wv.y;
            acc[0][2] += xv.x * wv.z; acc[0][3] += xv.x * wv.w;
            acc[1][0] += xv.y * wv.x; acc[1][1] += xv.y * wv.y;
            acc[1][2] += xv.y * wv.z; acc[1][3] += xv.y * wv.w;
            acc[2][0] += xv.z * wv.x; acc[2][1] += xv.z * wv.y;
            acc[2][2] += xv.z * wv.z; acc[2][3] += xv.z * wv.w;
            acc[3][0] += xv.w * wv.x; acc[3][1] += xv.w * wv.y;
            acc[3][2] += xv.w * wv.z; acc[3][3] += xv.w * wv.w;
        }
        __syncthreads();
    }
#pragma unroll
    for (int j = 0; j < 4; ++j) {
        const int row = bm + r4 + j;
        if (row < nrows) {
            const float4 o = make_float4(acc[j][0], acc[j][1], acc[j][2], acc[j][3]);
            *reinterpret_cast<float4*>(&S[(size_t)row * OUT_F + c4]) = o;
        }
    }
}

// ---------------- CSR build ----------------
__global__ void hist_kernel(const int* __restrict__ dst, int* __restrict__ counts, int E) {
    int i = blockIdx.x * blockDim.x + threadIdx.x;
    const int stride = gridDim.x * blockDim.x;
    for (; i < E; i += stride) atomicAdd(&counts[dst[i]], 1);
}

__global__ __launch_bounds__(256) void scan1_kernel(const int* __restrict__ counts,
                                                    int* __restrict__ off,
                                                    int* __restrict__ bsums, int n) {
    __shared__ int sd[256];
    const int t = threadIdx.x;
    const int base = blockIdx.x * SCAN_CHUNK + t * 4;
    int c[4]; int s = 0;
#pragma unroll
    for (int j = 0; j < 4; ++j) {
        c[j] = (base + j < n) ? counts[base + j] : 0;
        s += c[j];
    }
    sd[t] = s;
    __syncthreads();
    for (int d = 1; d < 256; d <<= 1) {
        int v = (t >= d) ? sd[t - d] : 0;
        __syncthreads();
        sd[t] += v;
        __syncthreads();
    }
    int run = sd[t] - s;  // exclusive prefix of this thread's 4
#pragma unroll
    for (int j = 0; j < 4; ++j) {
        if (base + j < n) off[base + j] = run;
        run += c[j];
    }
    if (t == 255) bsums[blockIdx.x] = sd[255];
}

__global__ __launch_bounds__(256) void scan2_kernel(int* __restrict__ bsums, int nb) {
    __shared__ int sd[256];
    const int t = threadIdx.x;
    const int v = (t < nb) ? bsums[t] : 0;
    sd[t] = v;
    __syncthreads();
    for (int d = 1; d < 256; d <<= 1) {
        int u = (t >= d) ? sd[t - d] : 0;
        __syncthreads();
        sd[t] += u;
        __syncthreads();
    }
    if (t < nb) bsums[t] = sd[t] - v;  // exclusive
}

__global__ __launch_bounds__(256) void scan3_kernel(int* __restrict__ off,
                                                    int* __restrict__ cursor,
                                                    const int* __restrict__ bsums,
                                                    int n, int total) {
    const int t = threadIdx.x;
    const int base = blockIdx.x * SCAN_CHUNK + t * 4;
    const int add = bsums[blockIdx.x];
#pragma unroll
    for (int j = 0; j < 4; ++j) {
        const int idx = base + j;
        if (idx < n) {
            const int v = off[idx] + add;
            off[idx] = v;
            cursor[idx] = v;
        }
    }
    if (blockIdx.x == 0 && t == 0) off[n] = total;
}

// Pack (src, weight-bits) into one int2 -> single 8B random store per edge.
__global__ void scatter_kernel(const int* __restrict__ src, const int* __restrict__ dst,
                               const float* __restrict__ w, int* __restrict__ cursor,
                               int2* __restrict__ pairs, int E) {
    int i = blockIdx.x * blockDim.x + threadIdx.x;
    const int stride = gridDim.x * blockDim.x;
    for (; i < E; i += stride) {
        const int d = dst[i];
        const int pos = atomicAdd(&cursor[d], 1);
        int2 p;
        p.x = src[i];
        p.y = __float_as_int(w[i]);
        pairs[pos] = p;
    }
}

// ---------------- Gather: out[n] = sum_e w_e * support[src_e] + B ----------------
// 2 nodes per 256-thread block; 128 threads (= OUT_F) per node, feature-parallel.
__global__ __launch_bounds__(256) void gather_kernel(const float* __restrict__ S,
                                                     const int* __restrict__ off,
                                                     const int2* __restrict__ pairs,
                                                     const float* __restrict__ B,
                                                     float* __restrict__ out, int n) {
    const int node = blockIdx.x * 2 + (threadIdx.x >> 7);
    const int f = threadIdx.x & 127;
    if (node >= n) return;
    const int s = off[node];
    const int e = off[node + 1];
    float acc0 = 0.f, acc1 = 0.f;
    int i = s;
    for (; i + 1 < e; i += 2) {
        const int2 p0 = pairs[i];
        const int2 p1 = pairs[i + 1];
        acc0 += __int_as_float(p0.y) * S[(size_t)p0.x * OUT_F + f];
        acc1 += __int_as_float(p1.y) * S[(size_t)p1.x * OUT_F + f];
    }
    if (i < e) {
        const int2 p = pairs[i];
        acc0 += __int_as_float(p.y) * S[(size_t)p.x * OUT_F + f];
    }
    out[(size_t)node * OUT_F + f] = acc0 + acc1 + B[f];
}

// ---------------- Fallback (small ws): direct f32 atomics ----------------
__global__ void init_out_kernel(float* __restrict__ out, const float* __restrict__ B, size_t n) {
    size_t i = (size_t)blockIdx.x * blockDim.x + threadIdx.x;
    const size_t stride = (size_t)gridDim.x * blockDim.x;
    for (; i < n; i += stride) out[i] = B[i & (OUT_F - 1)];
}

__global__ void atomic_scatter_kernel(const float* __restrict__ S, const int* __restrict__ src,
                                      const int* __restrict__ dst, const float* __restrict__ w,
                                      float* __restrict__ out, int E) {
    size_t i = (size_t)blockIdx.x * blockDim.x + threadIdx.x;
    const size_t stride = (size_t)gridDim.x * blockDim.x;
    const size_t total = (size_t)E * OUT_F;
    for (; i < total; i += stride) {
        const int e = (int)(i >> 7);
        const int f = (int)(i & 127);
        atomicAdd(&out[(size_t)dst[e] * OUT_F + f], w[e] * S[(size_t)src[e] * OUT_F + f]);
    }
}

extern "C" void kernel_launch(void* const* d_in, const int* in_sizes, int n_in,
                              void* d_out, int out_size, void* d_ws, size_t ws_size,
                              hipStream_t stream) {
    const float* X    = (const float*)d_in[0];
    const float* W    = (const float*)d_in[1];
    const float* B    = (const float*)d_in[2];
    const int*   esrc = (const int*)d_in[3];
    const int*   edst = (const int*)d_in[4];
    const float* ew   = (const float*)d_in[5];
    float* out = (float*)d_out;

    const int N = in_sizes[0] / IN_F;
    const int E = in_sizes[3];

    // workspace carve-out (256B aligned)
    char* ws = (char*)d_ws;
    size_t cur = 0;
    auto carve = [&](size_t bytes) -> void* {
        void* p = ws + cur;
        cur = (cur + bytes + 255) & ~(size_t)255;
        return p;
    };
    float* support = (float*)carve((size_t)N * OUT_F * sizeof(float));
    int*   counts  = (int*)carve((size_t)N * sizeof(int));
    int*   offs    = (int*)carve((size_t)(N + 1) * sizeof(int));
    int*   cursor  = (int*)carve((size_t)N * sizeof(int));
    int*   bsums   = (int*)carve(1024 * sizeof(int));
    int2*  pairs   = (int2*)carve((size_t)E * sizeof(int2));
    const bool csr_ok = (cur <= ws_size);

    const int gemm_grid = (N + 31) / 32;
    gemm_kernel<<<gemm_grid, 256, 0, stream>>>(X, W, support, N);

    if (csr_ok) {
        hipMemsetAsync(counts, 0, (size_t)N * sizeof(int), stream);
        hist_kernel<<<1024, 256, 0, stream>>>(edst, counts, E);
        const int nb = (N + SCAN_CHUNK - 1) / SCAN_CHUNK;  // 98 for N=100000 (<=256 supported)
        scan1_kernel<<<nb, 256, 0, stream>>>(counts, offs, bsums, N);
        scan2_kernel<<<1, 256, 0, stream>>>(bsums, nb);
        scan3_kernel<<<nb, 256, 0, stream>>>(offs, cursor, bsums, N, E);
        scatter_kernel<<<1024, 256, 0, stream>>>(esrc, edst, ew, cursor, pairs, E);
        gather_kernel<<<(N + 1) / 2, 256, 0, stream>>>(support, offs, pairs, B, out, N);
    } else {
        init_out_kernel<<<2048, 256, 0, stream>>>(out, B, (size_t)N * OUT_F);
        atomic_scatter_kernel<<<4096, 256, 0, stream>>>(support, esrc, edst, ew, out, E);
    }
}

// Round 3
// 546.963 us; speedup vs baseline: 1.1369x; 1.1369x over previous
//
#include <hip/hip_runtime.h>
#include <cstddef>

#define IN_F 256
#define OUT_F 128
#define SCAN_CHUNK 1024

// ---------------- GEMM: support = X @ W  (fp32, vector FMA) ----------------
// BM=64 rows, BN=128 cols (=OUT_F), BK=32. 256 threads; each thread 8x4 outputs.
// 32 FMA per 3 ds_read_b128; 25.6 KB LDS -> ~6 blocks/CU.
__global__ __launch_bounds__(256) void gemm_kernel(const float* __restrict__ X,
                                                   const float* __restrict__ W,
                                                   float* __restrict__ S,
                                                   int nrows) {
    __shared__ float Xs[32][68];    // [k][row], stride 68: b128-aligned (272B), 2-way-max read alias
    __shared__ float Ws[32][128];   // [k][col]
    const int t = threadIdx.x;
    const int bm = blockIdx.x * 64;
    const int tr = (t >> 5) * 8;    // 8 thread-rows x 8 outputs
    const int tc = (t & 31) * 4;    // 32 thread-cols x 4 outputs
    float acc[8][4] = {};

    for (int kt = 0; kt < IN_F; kt += 32) {
        // stage X tile transposed: 64 rows x 32 k = 512 float4, 2 per thread
#pragma unroll
        for (int l = 0; l < 2; ++l) {
            const int idx = t + l * 256;
            const int r = idx >> 3;      // 0..63
            const int k4 = idx & 7;      // float4 index along k
            int rr = bm + r; if (rr >= nrows) rr = nrows - 1;
            const float4 v = *reinterpret_cast<const float4*>(
                &X[(size_t)rr * IN_F + kt + k4 * 4]);
            Xs[k4 * 4 + 0][r] = v.x;
            Xs[k4 * 4 + 1][r] = v.y;
            Xs[k4 * 4 + 2][r] = v.z;
            Xs[k4 * 4 + 3][r] = v.w;
        }
        // stage W tile: 32 k x 128 c = 1024 float4, 4 per thread (linear, coalesced)
#pragma unroll
        for (int l = 0; l < 4; ++l) {
            const int q = t + l * 256;
            const int k = q >> 5;
            const int c = (q & 31) * 4;
            *reinterpret_cast<float4*>(&Ws[k][c]) =
                *reinterpret_cast<const float4*>(&W[(size_t)(kt + k) * OUT_F + c]);
        }
        __syncthreads();
#pragma unroll 4
        for (int kk = 0; kk < 32; ++kk) {
            const float4 x0 = *reinterpret_cast<const float4*>(&Xs[kk][tr]);
            const float4 x1 = *reinterpret_cast<const float4*>(&Xs[kk][tr + 4]);
            const float4 wv = *reinterpret_cast<const float4*>(&Ws[kk][tc]);
            const float xr[8] = {x0.x, x0.y, x0.z, x0.w, x1.x, x1.y, x1.z, x1.w};
#pragma unroll
            for (int j = 0; j < 8; ++j) {
                acc[j][0] += xr[j] * wv.x;
                acc[j][1] += xr[j] * wv.y;
                acc[j][2] += xr[j] * wv.z;
                acc[j][3] += xr[j] * wv.w;
            }
        }
        __syncthreads();
    }
#pragma unroll
    for (int j = 0; j < 8; ++j) {
        const int row = bm + tr + j;
        if (row < nrows) {
            *reinterpret_cast<float4*>(&S[(size_t)row * OUT_F + tc]) =
                make_float4(acc[j][0], acc[j][1], acc[j][2], acc[j][3]);
        }
    }
}

// ---------------- CSR build ----------------
__global__ void hist_kernel(const int* __restrict__ dst, int* __restrict__ counts, int E) {
    int i = blockIdx.x * blockDim.x + threadIdx.x;
    const int stride = gridDim.x * blockDim.x;
    for (; i < E; i += stride) atomicAdd(&counts[dst[i]], 1);
}

__global__ __launch_bounds__(256) void scan1_kernel(const int* __restrict__ counts,
                                                    int* __restrict__ off,
                                                    int* __restrict__ bsums, int n) {
    __shared__ int sd[256];
    const int t = threadIdx.x;
    const int base = blockIdx.x * SCAN_CHUNK + t * 4;
    int c[4]; int s = 0;
#pragma unroll
    for (int j = 0; j < 4; ++j) {
        c[j] = (base + j < n) ? counts[base + j] : 0;
        s += c[j];
    }
    sd[t] = s;
    __syncthreads();
    for (int d = 1; d < 256; d <<= 1) {
        int v = (t >= d) ? sd[t - d] : 0;
        __syncthreads();
        sd[t] += v;
        __syncthreads();
    }
    int run = sd[t] - s;  // exclusive prefix of this thread's 4
#pragma unroll
    for (int j = 0; j < 4; ++j) {
        if (base + j < n) off[base + j] = run;
        run += c[j];
    }
    if (t == 255) bsums[blockIdx.x] = sd[255];
}

__global__ __launch_bounds__(256) void scan2_kernel(int* __restrict__ bsums, int nb) {
    __shared__ int sd[256];
    const int t = threadIdx.x;
    const int v = (t < nb) ? bsums[t] : 0;
    sd[t] = v;
    __syncthreads();
    for (int d = 1; d < 256; d <<= 1) {
        int u = (t >= d) ? sd[t - d] : 0;
        __syncthreads();
        sd[t] += u;
        __syncthreads();
    }
    if (t < nb) bsums[t] = sd[t] - v;  // exclusive
}

__global__ __launch_bounds__(256) void scan3_kernel(int* __restrict__ off,
                                                    int* __restrict__ cursor,
                                                    const int* __restrict__ bsums,
                                                    int n, int total) {
    const int t = threadIdx.x;
    const int base = blockIdx.x * SCAN_CHUNK + t * 4;
    const int add = bsums[blockIdx.x];
#pragma unroll
    for (int j = 0; j < 4; ++j) {
        const int idx = base + j;
        if (idx < n) {
            const int v = off[idx] + add;
            off[idx] = v;
            cursor[idx] = v;
        }
    }
    if (blockIdx.x == 0 && t == 0) off[n] = total;
}

// Pack (src, weight-bits) into one int2 -> single 8B random store per edge.
__global__ void scatter_kernel(const int* __restrict__ src, const int* __restrict__ dst,
                               const float* __restrict__ w, int* __restrict__ cursor,
                               int2* __restrict__ pairs, int E) {
    int i = blockIdx.x * blockDim.x + threadIdx.x;
    const int stride = gridDim.x * blockDim.x;
    for (; i < E; i += stride) {
        const int d = dst[i];
        const int pos = atomicAdd(&cursor[d], 1);
        int2 p;
        p.x = src[i];
        p.y = __float_as_int(w[i]);
        pairs[pos] = p;
    }
}

// ---------------- Gather: out[n] = sum_e w_e * support[src_e] + B ----------------
// One 64-lane wave per node; each lane covers 2 features via float2 (512B/row/instr).
// 4-deep manual unroll: 4 independent pair->row load chains in flight per wave.
__global__ __launch_bounds__(256) void gather_kernel(const float* __restrict__ S,
                                                     const int* __restrict__ off,
                                                     const int2* __restrict__ pairs,
                                                     const float* __restrict__ B,
                                                     float* __restrict__ out, int n) {
    const int node = blockIdx.x * 4 + (threadIdx.x >> 6);
    const int lane = threadIdx.x & 63;
    if (node >= n) return;
    int i = off[node];
    const int e = off[node + 1];
    const size_t fo = (size_t)lane * 2;
    float ax = 0.f, ay = 0.f, bx = 0.f, by = 0.f;
    for (; i + 4 <= e; i += 4) {
        const int2 p0 = pairs[i];
        const int2 p1 = pairs[i + 1];
        const int2 p2 = pairs[i + 2];
        const int2 p3 = pairs[i + 3];
        const float2 v0 = *reinterpret_cast<const float2*>(&S[(size_t)p0.x * OUT_F + fo]);
        const float2 v1 = *reinterpret_cast<const float2*>(&S[(size_t)p1.x * OUT_F + fo]);
        const float2 v2 = *reinterpret_cast<const float2*>(&S[(size_t)p2.x * OUT_F + fo]);
        const float2 v3 = *reinterpret_cast<const float2*>(&S[(size_t)p3.x * OUT_F + fo]);
        const float w0 = __int_as_float(p0.y);
        const float w1 = __int_as_float(p1.y);
        const float w2 = __int_as_float(p2.y);
        const float w3 = __int_as_float(p3.y);
        ax += w0 * v0.x; ay += w0 * v0.y;
        bx += w1 * v1.x; by += w1 * v1.y;
        ax += w2 * v2.x; ay += w2 * v2.y;
        bx += w3 * v3.x; by += w3 * v3.y;
    }
    for (; i < e; ++i) {
        const int2 p = pairs[i];
        const float2 v = *reinterpret_cast<const float2*>(&S[(size_t)p.x * OUT_F + fo]);
        const float w = __int_as_float(p.y);
        ax += w * v.x; ay += w * v.y;
    }
    const float2 b2 = *reinterpret_cast<const float2*>(&B[fo]);
    float2 o;
    o.x = ax + bx + b2.x;
    o.y = ay + by + b2.y;
    *reinterpret_cast<float2*>(&out[(size_t)node * OUT_F + fo]) = o;
}

// ---------------- Fallback (small ws): direct f32 atomics ----------------
__global__ void init_out_kernel(float* __restrict__ out, const float* __restrict__ B, size_t n) {
    size_t i = (size_t)blockIdx.x * blockDim.x + threadIdx.x;
    const size_t stride = (size_t)gridDim.x * blockDim.x;
    for (; i < n; i += stride) out[i] = B[i & (OUT_F - 1)];
}

__global__ void atomic_scatter_kernel(const float* __restrict__ S, const int* __restrict__ src,
                                      const int* __restrict__ dst, const float* __restrict__ w,
                                      float* __restrict__ out, int E) {
    size_t i = (size_t)blockIdx.x * blockDim.x + threadIdx.x;
    const size_t stride = (size_t)gridDim.x * blockDim.x;
    const size_t total = (size_t)E * OUT_F;
    for (; i < total; i += stride) {
        const int e = (int)(i >> 7);
        const int f = (int)(i & 127);
        atomicAdd(&out[(size_t)dst[e] * OUT_F + f], w[e] * S[(size_t)src[e] * OUT_F + f]);
    }
}

extern "C" void kernel_launch(void* const* d_in, const int* in_sizes, int n_in,
                              void* d_out, int out_size, void* d_ws, size_t ws_size,
                              hipStream_t stream) {
    const float* X    = (const float*)d_in[0];
    const float* W    = (const float*)d_in[1];
    const float* B    = (const float*)d_in[2];
    const int*   esrc = (const int*)d_in[3];
    const int*   edst = (const int*)d_in[4];
    const float* ew   = (const float*)d_in[5];
    float* out = (float*)d_out;

    const int N = in_sizes[0] / IN_F;
    const int E = in_sizes[3];

    // workspace carve-out (256B aligned)
    char* ws = (char*)d_ws;
    size_t cur = 0;
    auto carve = [&](size_t bytes) -> void* {
        void* p = ws + cur;
        cur = (cur + bytes + 255) & ~(size_t)255;
        return p;
    };
    float* support = (float*)carve((size_t)N * OUT_F * sizeof(float));
    int*   counts  = (int*)carve((size_t)N * sizeof(int));
    int*   offs    = (int*)carve((size_t)(N + 1) * sizeof(int));
    int*   cursor  = (int*)carve((size_t)N * sizeof(int));
    int*   bsums   = (int*)carve(1024 * sizeof(int));
    int2*  pairs   = (int2*)carve((size_t)E * sizeof(int2));
    const bool csr_ok = (cur <= ws_size);

    const int gemm_grid = (N + 63) / 64;
    gemm_kernel<<<gemm_grid, 256, 0, stream>>>(X, W, support, N);

    if (csr_ok) {
        hipMemsetAsync(counts, 0, (size_t)N * sizeof(int), stream);
        hist_kernel<<<2048, 256, 0, stream>>>(edst, counts, E);
        const int nb = (N + SCAN_CHUNK - 1) / SCAN_CHUNK;  // 98 for N=100000 (<=256 supported)
        scan1_kernel<<<nb, 256, 0, stream>>>(counts, offs, bsums, N);
        scan2_kernel<<<1, 256, 0, stream>>>(bsums, nb);
        scan3_kernel<<<nb, 256, 0, stream>>>(offs, cursor, bsums, N, E);
        scatter_kernel<<<2048, 256, 0, stream>>>(esrc, edst, ew, cursor, pairs, E);
        gather_kernel<<<(N + 3) / 4, 256, 0, stream>>>(support, offs, pairs, B, out, N);
    } else {
        init_out_kernel<<<2048, 256, 0, stream>>>(out, B, (size_t)N * OUT_F);
        atomic_scatter_kernel<<<4096, 256, 0, stream>>>(support, esrc, edst, ew, out, E);
    }
}

// Round 4
// 509.182 us; speedup vs baseline: 1.2212x; 1.0742x over previous
//
#include <hip/hip_runtime.h>
#include <cstddef>

#define IN_F 256
#define OUT_F 128
#define SCAN_CHUNK 1024
#define RANGES 16
#define SCHUNKS 512

// ---------------- GEMM: support = X @ W  (fp32, vector FMA) ----------------
// BM=64 rows, BN=128 cols (=OUT_F), BK=32. 256 threads; each thread 8x4 outputs.
// 32 FMA per 3 ds_read_b128; 25.6 KB LDS -> ~6 blocks/CU.
__global__ __launch_bounds__(256) void gemm_kernel(const float* __restrict__ X,
                                                   const float* __restrict__ W,
                                                   float* __restrict__ S,
                                                   int nrows) {
    __shared__ float Xs[32][68];    // [k][row], stride 68: b128-aligned (272B), 2-way-max read alias
    __shared__ float Ws[32][128];   // [k][col]
    const int t = threadIdx.x;
    const int bm = blockIdx.x * 64;
    const int tr = (t >> 5) * 8;    // 8 thread-rows x 8 outputs
    const int tc = (t & 31) * 4;    // 32 thread-cols x 4 outputs
    float acc[8][4] = {};

    for (int kt = 0; kt < IN_F; kt += 32) {
        // stage X tile transposed: 64 rows x 32 k = 512 float4, 2 per thread
#pragma unroll
        for (int l = 0; l < 2; ++l) {
            const int idx = t + l * 256;
            const int r = idx >> 3;      // 0..63
            const int k4 = idx & 7;      // float4 index along k
            int rr = bm + r; if (rr >= nrows) rr = nrows - 1;
            const float4 v = *reinterpret_cast<const float4*>(
                &X[(size_t)rr * IN_F + kt + k4 * 4]);
            Xs[k4 * 4 + 0][r] = v.x;
            Xs[k4 * 4 + 1][r] = v.y;
            Xs[k4 * 4 + 2][r] = v.z;
            Xs[k4 * 4 + 3][r] = v.w;
        }
        // stage W tile: 32 k x 128 c = 1024 float4, 4 per thread (linear, coalesced)
#pragma unroll
        for (int l = 0; l < 4; ++l) {
            const int q = t + l * 256;
            const int k = q >> 5;
            const int c = (q & 31) * 4;
            *reinterpret_cast<float4*>(&Ws[k][c]) =
                *reinterpret_cast<const float4*>(&W[(size_t)(kt + k) * OUT_F + c]);
        }
        __syncthreads();
#pragma unroll 4
        for (int kk = 0; kk < 32; ++kk) {
            const float4 x0 = *reinterpret_cast<const float4*>(&Xs[kk][tr]);
            const float4 x1 = *reinterpret_cast<const float4*>(&Xs[kk][tr + 4]);
            const float4 wv = *reinterpret_cast<const float4*>(&Ws[kk][tc]);
            const float xr[8] = {x0.x, x0.y, x0.z, x0.w, x1.x, x1.y, x1.z, x1.w};
#pragma unroll
            for (int j = 0; j < 8; ++j) {
                acc[j][0] += xr[j] * wv.x;
                acc[j][1] += xr[j] * wv.y;
                acc[j][2] += xr[j] * wv.z;
                acc[j][3] += xr[j] * wv.w;
            }
        }
        __syncthreads();
    }
#pragma unroll
    for (int j = 0; j < 8; ++j) {
        const int row = bm + tr + j;
        if (row < nrows) {
            *reinterpret_cast<float4*>(&S[(size_t)row * OUT_F + tc]) =
                make_float4(acc[j][0], acc[j][1], acc[j][2], acc[j][3]);
        }
    }
}

// ---------------- CSR build ----------------
__global__ void hist_kernel(const int* __restrict__ dst, int* __restrict__ counts, int E) {
    int i = blockIdx.x * blockDim.x + threadIdx.x;
    const int stride = gridDim.x * blockDim.x;
    for (; i < E; i += stride) atomicAdd(&counts[dst[i]], 1);
}

__global__ __launch_bounds__(256) void scan1_kernel(const int* __restrict__ counts,
                                                    int* __restrict__ off,
                                                    int* __restrict__ bsums, int n) {
    __shared__ int sd[256];
    const int t = threadIdx.x;
    const int base = blockIdx.x * SCAN_CHUNK + t * 4;
    int c[4]; int s = 0;
#pragma unroll
    for (int j = 0; j < 4; ++j) {
        c[j] = (base + j < n) ? counts[base + j] : 0;
        s += c[j];
    }
    sd[t] = s;
    __syncthreads();
    for (int d = 1; d < 256; d <<= 1) {
        int v = (t >= d) ? sd[t - d] : 0;
        __syncthreads();
        sd[t] += v;
        __syncthreads();
    }
    int run = sd[t] - s;  // exclusive prefix of this thread's 4
#pragma unroll
    for (int j = 0; j < 4; ++j) {
        if (base + j < n) off[base + j] = run;
        run += c[j];
    }
    if (t == 255) bsums[blockIdx.x] = sd[255];
}

__global__ __launch_bounds__(256) void scan2_kernel(int* __restrict__ bsums, int nb) {
    __shared__ int sd[256];
    const int t = threadIdx.x;
    const int v = (t < nb) ? bsums[t] : 0;
    sd[t] = v;
    __syncthreads();
    for (int d = 1; d < 256; d <<= 1) {
        int u = (t >= d) ? sd[t - d] : 0;
        __syncthreads();
        sd[t] += u;
        __syncthreads();
    }
    if (t < nb) bsums[t] = sd[t] - v;  // exclusive
}

__global__ __launch_bounds__(256) void scan3_kernel(int* __restrict__ off,
                                                    int* __restrict__ cursor,
                                                    const int* __restrict__ bsums,
                                                    int n, int total) {
    const int t = threadIdx.x;
    const int base = blockIdx.x * SCAN_CHUNK + t * 4;
    const int add = bsums[blockIdx.x];
#pragma unroll
    for (int j = 0; j < 4; ++j) {
        const int idx = base + j;
        if (idx < n) {
            const int v = off[idx] + add;
            off[idx] = v;
            cursor[idx] = v;
        }
    }
    if (blockIdx.x == 0 && t == 0) off[n] = total;
}

// ---------------- Ranged scatter ----------------
// dst-range-partitioned: blockIdx = range*SCHUNKS + chunk (range-major => ranges
// execute roughly in dispatch order). Each range's pairs write-window is only
// E/RANGES*8B = 0.8MB, so L2 lines accumulate all 8 pairs before writeback —
// kills the 8x partial-line write amplification seen in round 3 (100MB HBM writes).
__global__ __launch_bounds__(256) void scatter_kernel(const int* __restrict__ src,
                                                      const int* __restrict__ dst,
                                                      const float* __restrict__ w,
                                                      int* __restrict__ cursor,
                                                      int2* __restrict__ pairs,
                                                      int E, int nodes_per_range) {
    const int range = blockIdx.x / SCHUNKS;
    const int chunk = blockIdx.x % SCHUNKS;
    const int r_lo = range * nodes_per_range;
    const int r_hi = r_lo + nodes_per_range;
    const int per_chunk = (E + SCHUNKS - 1) / SCHUNKS;
    const int start = chunk * per_chunk;
    const int end = min(E, start + per_chunk);
    for (int i = start + threadIdx.x; i < end; i += 256) {
        const int d = dst[i];
        if (d >= r_lo && d < r_hi) {
            const int pos = atomicAdd(&cursor[d], 1);
            int2 p;
            p.x = src[i];
            p.y = __float_as_int(w[i]);
            pairs[pos] = p;
        }
    }
}

// ---------------- Gather: out[n] = sum_e w_e * support[src_e] + B ----------------
// One 64-lane wave per node; each lane covers 2 features via float2 (512B/row/instr).
// 4-deep manual unroll: 4 independent pair->row load chains in flight per wave.
__global__ __launch_bounds__(256) void gather_kernel(const float* __restrict__ S,
                                                     const int* __restrict__ off,
                                                     const int2* __restrict__ pairs,
                                                     const float* __restrict__ B,
                                                     float* __restrict__ out, int n) {
    const int node = blockIdx.x * 4 + (threadIdx.x >> 6);
    const int lane = threadIdx.x & 63;
    if (node >= n) return;
    int i = off[node];
    const int e = off[node + 1];
    const size_t fo = (size_t)lane * 2;
    float ax = 0.f, ay = 0.f, bx = 0.f, by = 0.f;
    for (; i + 4 <= e; i += 4) {
        const int2 p0 = pairs[i];
        const int2 p1 = pairs[i + 1];
        const int2 p2 = pairs[i + 2];
        const int2 p3 = pairs[i + 3];
        const float2 v0 = *reinterpret_cast<const float2*>(&S[(size_t)p0.x * OUT_F + fo]);
        const float2 v1 = *reinterpret_cast<const float2*>(&S[(size_t)p1.x * OUT_F + fo]);
        const float2 v2 = *reinterpret_cast<const float2*>(&S[(size_t)p2.x * OUT_F + fo]);
        const float2 v3 = *reinterpret_cast<const float2*>(&S[(size_t)p3.x * OUT_F + fo]);
        const float w0 = __int_as_float(p0.y);
        const float w1 = __int_as_float(p1.y);
        const float w2 = __int_as_float(p2.y);
        const float w3 = __int_as_float(p3.y);
        ax += w0 * v0.x; ay += w0 * v0.y;
        bx += w1 * v1.x; by += w1 * v1.y;
        ax += w2 * v2.x; ay += w2 * v2.y;
        bx += w3 * v3.x; by += w3 * v3.y;
    }
    for (; i < e; ++i) {
        const int2 p = pairs[i];
        const float2 v = *reinterpret_cast<const float2*>(&S[(size_t)p.x * OUT_F + fo]);
        const float w = __int_as_float(p.y);
        ax += w * v.x; ay += w * v.y;
    }
    const float2 b2 = *reinterpret_cast<const float2*>(&B[fo]);
    float2 o;
    o.x = ax + bx + b2.x;
    o.y = ay + by + b2.y;
    *reinterpret_cast<float2*>(&out[(size_t)node * OUT_F + fo]) = o;
}

// ---------------- Fallback (small ws): direct f32 atomics ----------------
__global__ void init_out_kernel(float* __restrict__ out, const float* __restrict__ B, size_t n) {
    size_t i = (size_t)blockIdx.x * blockDim.x + threadIdx.x;
    const size_t stride = (size_t)gridDim.x * blockDim.x;
    for (; i < n; i += stride) out[i] = B[i & (OUT_F - 1)];
}

__global__ void atomic_scatter_kernel(const float* __restrict__ S, const int* __restrict__ src,
                                      const int* __restrict__ dst, const float* __restrict__ w,
                                      float* __restrict__ out, int E) {
    size_t i = (size_t)blockIdx.x * blockDim.x + threadIdx.x;
    const size_t stride = (size_t)gridDim.x * blockDim.x;
    const size_t total = (size_t)E * OUT_F;
    for (; i < total; i += stride) {
        const int e = (int)(i >> 7);
        const int f = (int)(i & 127);
        atomicAdd(&out[(size_t)dst[e] * OUT_F + f], w[e] * S[(size_t)src[e] * OUT_F + f]);
    }
}

extern "C" void kernel_launch(void* const* d_in, const int* in_sizes, int n_in,
                              void* d_out, int out_size, void* d_ws, size_t ws_size,
                              hipStream_t stream) {
    const float* X    = (const float*)d_in[0];
    const float* W    = (const float*)d_in[1];
    const float* B    = (const float*)d_in[2];
    const int*   esrc = (const int*)d_in[3];
    const int*   edst = (const int*)d_in[4];
    const float* ew   = (const float*)d_in[5];
    float* out = (float*)d_out;

    const int N = in_sizes[0] / IN_F;
    const int E = in_sizes[3];

    // workspace carve-out (256B aligned)
    char* ws = (char*)d_ws;
    size_t cur = 0;
    auto carve = [&](size_t bytes) -> void* {
        void* p = ws + cur;
        cur = (cur + bytes + 255) & ~(size_t)255;
        return p;
    };
    float* support = (float*)carve((size_t)N * OUT_F * sizeof(float));
    int*   counts  = (int*)carve((size_t)N * sizeof(int));
    int*   offs    = (int*)carve((size_t)(N + 1) * sizeof(int));
    int*   cursor  = (int*)carve((size_t)N * sizeof(int));
    int*   bsums   = (int*)carve(1024 * sizeof(int));
    int2*  pairs   = (int2*)carve((size_t)E * sizeof(int2));
    const bool csr_ok = (cur <= ws_size);

    const int gemm_grid = (N + 63) / 64;
    gemm_kernel<<<gemm_grid, 256, 0, stream>>>(X, W, support, N);

    if (csr_ok) {
        hipMemsetAsync(counts, 0, (size_t)N * sizeof(int), stream);
        hist_kernel<<<2048, 256, 0, stream>>>(edst, counts, E);
        const int nb = (N + SCAN_CHUNK - 1) / SCAN_CHUNK;  // 98 for N=100000 (<=256 supported)
        scan1_kernel<<<nb, 256, 0, stream>>>(counts, offs, bsums, N);
        scan2_kernel<<<1, 256, 0, stream>>>(bsums, nb);
        scan3_kernel<<<nb, 256, 0, stream>>>(offs, cursor, bsums, N, E);
        const int npr = (N + RANGES - 1) / RANGES;
        scatter_kernel<<<RANGES * SCHUNKS, 256, 0, stream>>>(esrc, edst, ew, cursor, pairs, E, npr);
        gather_kernel<<<(N + 3) / 4, 256, 0, stream>>>(support, offs, pairs, B, out, N);
    } else {
        init_out_kernel<<<2048, 256, 0, stream>>>(out, B, (size_t)N * OUT_F);
        atomic_scatter_kernel<<<4096, 256, 0, stream>>>(support, esrc, edst, ew, out, E);
    }
}